// Round 3
// baseline (684.248 us; speedup 1.0000x reference)
//
#include <hip/hip_runtime.h>
#include <math.h>

// ---------------- CSR build ----------------

__global__ void detect_kernel(const void* edges, int nnode, int* flag) {
  // Decide whether edge_index is stored as int64 or int32.
  const long long* q = (const long long*)edges;
  bool ok = true;
  for (int i = 0; i < 8; ++i) {
    long long v = q[i];
    if (v < 0 || v >= (long long)nnode) ok = false;
  }
  *flag = ok ? 1 : 0;
}

__global__ void convert_kernel(const void* edges, int E, int N, const int* __restrict__ flag,
                               int* __restrict__ src32, int* __restrict__ dst32,
                               int* __restrict__ counts) {
  int i = blockIdx.x * blockDim.x + threadIdx.x;
  int tot = E + N;
  if (i >= tot) return;
  int s, d;
  if (i < E) {
    if (*flag) {
      s = (int)((const long long*)edges)[i];
      d = (int)((const long long*)edges)[E + i];
    } else {
      s = ((const int*)edges)[i];
      d = ((const int*)edges)[E + i];
    }
  } else {  // self loops
    s = d = i - E;
  }
  src32[i] = s;
  dst32[i] = d;
  atomicAdd(&counts[d], 1);
}

__global__ __launch_bounds__(1024) void prefix_kernel(const int* __restrict__ counts,
                                                      int* __restrict__ rowptr,
                                                      int* __restrict__ cursor, int n) {
  __shared__ int sums[1024];
  int t = threadIdx.x;
  int chunk = (n + 1023) / 1024;
  int start = t * chunk;
  int end = min(start + chunk, n);
  int s = 0;
  for (int i = start; i < end; ++i) s += counts[i];
  sums[t] = s;
  __syncthreads();
  for (int off = 1; off < 1024; off <<= 1) {
    int v = (t >= off) ? sums[t - off] : 0;
    __syncthreads();
    sums[t] += v;
    __syncthreads();
  }
  int run = (t == 0) ? 0 : sums[t - 1];
  for (int i = start; i < end; ++i) {
    rowptr[i] = run;
    cursor[i] = run;
    run += counts[i];
  }
  if (t == 1023) rowptr[n] = sums[1023];
}

__global__ void scatter_kernel(const int* __restrict__ src32, const int* __restrict__ dst32,
                               int* __restrict__ cursor, int* __restrict__ csr_src, int tot) {
  int i = blockIdx.x * blockDim.x + threadIdx.x;
  if (i >= tot) return;
  int d = dst32[i];
  int slot = atomicAdd(&cursor[d], 1);
  csr_src[slot] = src32[i];
}

// ---------------- fp32 GEMM: [N,128] @ [128,C] ----------------
// 128x128 output tile per 256-thread block, 8x8 micro-tile.
// K=128 processed in two BK=64 stages -> LDS 66 KB -> 2 blocks/CU
// (2 waves/SIMD) for latency hiding. A tile stored transposed in LDS
// so compute-phase reads are contiguous float4.

__global__ __launch_bounds__(256, 2) void gemm128_kernel(const float* __restrict__ A,
                                                         const float* __restrict__ B,
                                                         float* __restrict__ C,
                                                         int Nrows, int Ccols) {
  __shared__ float As[64][132];  // As[k][r] = A[row0+r][ks*64+k]
  __shared__ float Bs[64][132];  // Bs[k][c] = B[ks*64+k][col0+c]
  int t = threadIdx.x;
  int row0 = blockIdx.x * 128;
  int col0 = blockIdx.y * 128;
  int tx = t & 15, ty = t >> 4;

  float acc[8][8];
#pragma unroll
  for (int r = 0; r < 8; ++r)
#pragma unroll
    for (int c = 0; c < 8; ++c) acc[r][c] = 0.f;

  for (int ks = 0; ks < 2; ++ks) {
    if (ks) __syncthreads();  // protect LDS reuse across stages
    int k0 = ks * 64;
    // A: 128 rows x 16 quad-columns = 2048 float4 / 256 thr = 8 iters
#pragma unroll
    for (int i = 0; i < 8; ++i) {
      int q = t + i * 256;
      int r = q >> 4;            // 0..127
      int kc = (q & 15) << 2;    // 0..60
      int gr = row0 + r;
      float4 v = make_float4(0.f, 0.f, 0.f, 0.f);
      if (gr < Nrows) v = *(const float4*)(A + (size_t)gr * 128 + k0 + kc);
      As[kc + 0][r] = v.x;
      As[kc + 1][r] = v.y;
      As[kc + 2][r] = v.z;
      As[kc + 3][r] = v.w;
    }
    // B: 64 rows x 32 quad-columns = 2048 float4 / 256 thr = 8 iters
#pragma unroll
    for (int i = 0; i < 8; ++i) {
      int q = t + i * 256;
      int k = q >> 5;            // 0..63
      int c = (q & 31) << 2;     // 0..124
      *(float4*)(&Bs[k][c]) = *(const float4*)(B + (size_t)(k0 + k) * Ccols + col0 + c);
    }
    __syncthreads();

#pragma unroll 8
    for (int k = 0; k < 64; ++k) {
      float a[8], b[8];
      *(float4*)(a) = *(const float4*)(&As[k][ty * 8]);
      *(float4*)(a + 4) = *(const float4*)(&As[k][ty * 8 + 4]);
      *(float4*)(b) = *(const float4*)(&Bs[k][tx * 8]);
      *(float4*)(b + 4) = *(const float4*)(&Bs[k][tx * 8 + 4]);
#pragma unroll
      for (int r = 0; r < 8; ++r)
#pragma unroll
        for (int c = 0; c < 8; ++c) acc[r][c] = fmaf(a[r], b[c], acc[r][c]);
    }
  }

#pragma unroll
  for (int r = 0; r < 8; ++r) {
    int gr = row0 + ty * 8 + r;
    if (gr < Nrows) {
      float4* o = (float4*)(C + (size_t)gr * Ccols + col0 + tx * 8);
      o[0] = make_float4(acc[r][0], acc[r][1], acc[r][2], acc[r][3]);
      o[1] = make_float4(acc[r][4], acc[r][5], acc[r][6], acc[r][7]);
    }
  }
}

// ---------------- per-node attention scalars ----------------

template <int C>
__global__ void scalars_kernel(const float* __restrict__ h, const float* __restrict__ a_src,
                               const float* __restrict__ a_dst, float* __restrict__ as_,
                               float* __restrict__ ad_, int N) {
  int wid = (blockIdx.x * blockDim.x + threadIdx.x) >> 6;
  int lane = threadIdx.x & 63;
  if (wid >= N) return;
  const float* hr = h + (size_t)wid * C;
  float s1 = 0.f, s2 = 0.f;
#pragma unroll
  for (int c = lane; c < C; c += 64) {
    float v = hr[c];
    s1 += v * a_src[c];
    s2 += v * a_dst[c];
  }
#pragma unroll
  for (int off = 32; off; off >>= 1) {
    s1 += __shfl_xor(s1, off);
    s2 += __shfl_xor(s2, off);
  }
  if (lane == 0) {
    as_[wid] = s1;
    ad_[wid] = s2;
  }
}

// ---------------- per-dst online-softmax aggregation ----------------
// One wave per destination node; flash-style running (max,sum); features in regs.

template <int NC, bool RELU>
__global__ __launch_bounds__(256) void aggregate_kernel(
    const float* __restrict__ h, const float* __restrict__ res_in,
    const float* __restrict__ bias, const float* __restrict__ as_,
    const float* __restrict__ ad_, const int* __restrict__ rowptr,
    const int* __restrict__ csr_src, float* __restrict__ out, int N) {
  int wid = blockIdx.x * 4 + (threadIdx.x >> 6);
  int lane = threadIdx.x & 63;
  if (wid >= N) return;
  int base = rowptr[wid];
  int deg = rowptr[wid + 1] - base;
  float adn = ad_[wid];
  float m = -1e30f, ssum = 0.f;
  float acc[NC];
#pragma unroll
  for (int c = 0; c < NC; ++c) acc[c] = 0.f;
  for (int b0 = 0; b0 < deg; b0 += 64) {
    int idx = b0 + lane;
    int s = 0;
    float logit = -1e30f;
    if (idx < deg) {
      s = csr_src[base + idx];
      float tt = as_[s] + adn;
      logit = tt > 0.f ? tt : 0.2f * tt;  // LeakyReLU 0.2
    }
    float cm = logit;
#pragma unroll
    for (int off = 32; off; off >>= 1) cm = fmaxf(cm, __shfl_xor(cm, off));
    float mnew = fmaxf(m, cm);
    float scale = __expf(m - mnew);  // first chunk: exp(-huge) = 0
    ssum *= scale;
#pragma unroll
    for (int c = 0; c < NC; ++c) acc[c] *= scale;
    float p = (idx < deg) ? __expf(logit - mnew) : 0.f;
    float ps = p;
#pragma unroll
    for (int off = 32; off; off >>= 1) ps += __shfl_xor(ps, off);
    ssum += ps;
    int cnt = min(64, deg - b0);
    for (int j = 0; j < cnt; ++j) {
      float pj = __shfl(p, j);
      int sj = __shfl(s, j);
      const float* hs = h + (size_t)sj * (NC * 64);
#pragma unroll
      for (int c = 0; c < NC; ++c) acc[c] = fmaf(pj, hs[lane + 64 * c], acc[c]);
    }
    m = mnew;
  }
  float inv = 1.f / ssum;
  size_t o = (size_t)wid * (NC * 64);
#pragma unroll
  for (int c = 0; c < NC; ++c) {
    float v = acc[c] * inv + res_in[o + lane + 64 * c] + bias[lane + 64 * c];
    if (RELU) v = fmaxf(v, 0.f);
    out[o + lane + 64 * c] = v;
  }
}

// ---------------- launch ----------------

extern "C" void kernel_launch(void* const* d_in, const int* in_sizes, int n_in,
                              void* d_out, int out_size, void* d_ws, size_t ws_size,
                              hipStream_t stream) {
  const float* x = (const float*)d_in[0];
  const void* edges = d_in[1];
  const float* W1 = (const float*)d_in[2];
  const float* a_src1 = (const float*)d_in[3];
  const float* a_dst1 = (const float*)d_in[4];
  const float* b1 = (const float*)d_in[5];
  const float* Wres1 = (const float*)d_in[6];
  const float* W2 = (const float*)d_in[7];
  const float* a_src2 = (const float*)d_in[8];
  const float* a_dst2 = (const float*)d_in[9];
  const float* b2 = (const float*)d_in[10];
  const float* Wres2 = (const float*)d_in[11];
  float* out = (float*)d_out;

  int N = in_sizes[0] / 128;
  int E = in_sizes[1] / 2;
  int TOT = E + N;

  char* w = (char*)d_ws;
  size_t off = 0;
  auto alloc = [&](size_t bytes) {
    char* p = w + off;
    off += (bytes + 255) & ~(size_t)255;
    return p;
  };
  int* flag = (int*)alloc(4);
  int* counts = (int*)alloc((size_t)N * 4);
  int* cursor = (int*)alloc((size_t)N * 4);
  int* rowptr = (int*)alloc((size_t)(N + 1) * 4);
  float* as_ = (float*)alloc((size_t)N * 4);
  float* ad_ = (float*)alloc((size_t)N * 4);
  int* src32 = (int*)alloc((size_t)TOT * 4);
  int* dst32 = (int*)alloc((size_t)TOT * 4);
  int* csr = (int*)alloc((size_t)TOT * 4);
  float* hbuf = (float*)alloc((size_t)N * 256 * 4);   // h (layer1 uses 128, layer2 256)
  float* out1 = (float*)alloc((size_t)N * 128 * 4);   // layer-1 res, then layer-1 output

  hipMemsetAsync(counts, 0, (size_t)N * 4, stream);
  detect_kernel<<<1, 1, 0, stream>>>(edges, N, flag);
  int gb = (TOT + 255) / 256;
  convert_kernel<<<gb, 256, 0, stream>>>(edges, E, N, flag, src32, dst32, counts);
  prefix_kernel<<<1, 1024, 0, stream>>>(counts, rowptr, cursor, N);
  scatter_kernel<<<gb, 256, 0, stream>>>(src32, dst32, cursor, csr, TOT);

  int rb = (N + 127) / 128;
  int sb = (N + 3) / 4;

  // layer 1 (C=128)
  gemm128_kernel<<<dim3(rb, 1), 256, 0, stream>>>(x, W1, hbuf, N, 128);
  gemm128_kernel<<<dim3(rb, 1), 256, 0, stream>>>(x, Wres1, out1, N, 128);
  scalars_kernel<128><<<sb, 256, 0, stream>>>(hbuf, a_src1, a_dst1, as_, ad_, N);
  aggregate_kernel<2, true><<<sb, 256, 0, stream>>>(hbuf, out1, b1, as_, ad_, rowptr, csr, out1, N);

  // layer 2 (C=256)
  gemm128_kernel<<<dim3(rb, 2), 256, 0, stream>>>(out1, W2, hbuf, N, 256);
  gemm128_kernel<<<dim3(rb, 2), 256, 0, stream>>>(out1, Wres2, out, N, 256);
  scalars_kernel<256><<<sb, 256, 0, stream>>>(hbuf, a_src2, a_dst2, as_, ad_, N);
  aggregate_kernel<4, false><<<sb, 256, 0, stream>>>(hbuf, out, b2, as_, ad_, rowptr, csr, out, N);
}

// Round 4
// 534.489 us; speedup vs baseline: 1.2802x; 1.2802x over previous
//
#include <hip/hip_runtime.h>
#include <math.h>

typedef __attribute__((ext_vector_type(8))) short bf16x8;
typedef __attribute__((ext_vector_type(4))) float f32x4;

__device__ inline unsigned short f2bf(float f) {
  union { float f; unsigned u; } x; x.f = f;
  unsigned r = x.u + 0x7FFF + ((x.u >> 16) & 1);
  return (unsigned short)(r >> 16);
}
__device__ inline float bf2f(unsigned short b) {
  union { unsigned u; float f; } x; x.u = ((unsigned)b) << 16;
  return x.f;
}

// ---------------- CSR build (unchanged from passing round) ----------------

__global__ void detect_kernel(const void* edges, int nnode, int* flag) {
  const long long* q = (const long long*)edges;
  bool ok = true;
  for (int i = 0; i < 8; ++i) {
    long long v = q[i];
    if (v < 0 || v >= (long long)nnode) ok = false;
  }
  *flag = ok ? 1 : 0;
}

__global__ void convert_kernel(const void* edges, int E, int N, const int* __restrict__ flag,
                               int* __restrict__ src32, int* __restrict__ dst32,
                               int* __restrict__ counts) {
  int i = blockIdx.x * blockDim.x + threadIdx.x;
  int tot = E + N;
  if (i >= tot) return;
  int s, d;
  if (i < E) {
    if (*flag) {
      s = (int)((const long long*)edges)[i];
      d = (int)((const long long*)edges)[E + i];
    } else {
      s = ((const int*)edges)[i];
      d = ((const int*)edges)[E + i];
    }
  } else {
    s = d = i - E;
  }
  src32[i] = s;
  dst32[i] = d;
  atomicAdd(&counts[d], 1);
}

__global__ __launch_bounds__(1024) void prefix_kernel(const int* __restrict__ counts,
                                                      int* __restrict__ rowptr,
                                                      int* __restrict__ cursor, int n) {
  __shared__ int sums[1024];
  int t = threadIdx.x;
  int chunk = (n + 1023) / 1024;
  int start = t * chunk;
  int end = min(start + chunk, n);
  int s = 0;
  for (int i = start; i < end; ++i) s += counts[i];
  sums[t] = s;
  __syncthreads();
  for (int off = 1; off < 1024; off <<= 1) {
    int v = (t >= off) ? sums[t - off] : 0;
    __syncthreads();
    sums[t] += v;
    __syncthreads();
  }
  int run = (t == 0) ? 0 : sums[t - 1];
  for (int i = start; i < end; ++i) {
    rowptr[i] = run;
    cursor[i] = run;
    run += counts[i];
  }
  if (t == 1023) rowptr[n] = sums[1023];
}

__global__ void scatter_kernel(const int* __restrict__ src32, const int* __restrict__ dst32,
                               int* __restrict__ cursor, int* __restrict__ csr_src, int tot) {
  int i = blockIdx.x * blockDim.x + threadIdx.x;
  if (i >= tot) return;
  int d = dst32[i];
  int slot = atomicAdd(&cursor[d], 1);
  csr_src[slot] = src32[i];
}

// ---------------- dtype conversion ----------------

// x fp32 [N][128] -> bf16 [Mpad][128], pad rows zeroed. 4 elems/thread.
__global__ void cvt_x_kernel(const float* __restrict__ x, unsigned short* __restrict__ x16,
                             int N, int Mpad) {
  int tid = blockIdx.x * blockDim.x + threadIdx.x;
  if (tid >= Mpad * 32) return;
  int row = tid >> 5;
  int q = (tid & 31) << 2;
  unsigned short o0 = 0, o1 = 0, o2 = 0, o3 = 0;
  if (row < N) {
    float4 v = *(const float4*)(x + (size_t)row * 128 + q);
    o0 = f2bf(v.x); o1 = f2bf(v.y); o2 = f2bf(v.z); o3 = f2bf(v.w);
  }
  unsigned short* p = x16 + (size_t)row * 128 + q;
  p[0] = o0; p[1] = o1; p[2] = o2; p[3] = o3;
}

// W fp32 [128][C] -> Wt bf16 [C][128]
__global__ void cvt_wt_kernel(const float* __restrict__ W, unsigned short* __restrict__ Wt, int C) {
  int tid = blockIdx.x * blockDim.x + threadIdx.x;
  if (tid >= C * 128) return;
  int c = tid >> 7;
  int k = tid & 127;
  Wt[(size_t)c * 128 + k] = f2bf(W[(size_t)k * C + c]);
}

// ---------------- bf16 MFMA GEMM: [Mpad][128] @ Wt[C][128]^T ----------------
// No LDS: weights (<=64KB) are L1/L2 resident; fragments loaded direct.
// Wave computes 64x64 output. MODE 0: bf16 store; 1: bf16 store + bias; 2: f32 store + bias.

template <int MODE>
__global__ __launch_bounds__(256) void gemm_mfma(const unsigned short* __restrict__ A,
                                                 const unsigned short* __restrict__ Bt,
                                                 void* __restrict__ Cout,
                                                 const float* __restrict__ bias,
                                                 int Nrows, int Ctot) {
  int l = threadIdx.x & 63;
  int w = threadIdx.x >> 6;
  int row_w = blockIdx.x * 128 + (w & 1) * 64;
  int col_w = blockIdx.y * 128 + (w >> 1) * 64;
  int lo = l & 15, hi = l >> 4;
  f32x4 acc[4][4];
#pragma unroll
  for (int i = 0; i < 4; ++i)
#pragma unroll
    for (int j = 0; j < 4; ++j) acc[i][j] = (f32x4){0.f, 0.f, 0.f, 0.f};

  const unsigned short* Ap = A + (size_t)(row_w + lo) * 128 + hi * 8;
  const unsigned short* Bp = Bt + (size_t)(col_w + lo) * 128 + hi * 8;
#pragma unroll
  for (int kk = 0; kk < 4; ++kk) {
    bf16x8 a[4], b[4];
#pragma unroll
    for (int f = 0; f < 4; ++f) {
      a[f] = *(const bf16x8*)(Ap + (size_t)f * 16 * 128 + kk * 32);
      b[f] = *(const bf16x8*)(Bp + (size_t)f * 16 * 128 + kk * 32);
    }
#pragma unroll
    for (int fr = 0; fr < 4; ++fr)
#pragma unroll
      for (int fc = 0; fc < 4; ++fc)
        acc[fr][fc] = __builtin_amdgcn_mfma_f32_16x16x32_bf16(a[fr], b[fc], acc[fr][fc], 0, 0, 0);
  }
  // D layout: col = lane&15, row = (lane>>4)*4 + reg   [m89-verified]
#pragma unroll
  for (int fr = 0; fr < 4; ++fr) {
#pragma unroll
    for (int r = 0; r < 4; ++r) {
      int row = row_w + fr * 16 + hi * 4 + r;
      if (row < Nrows) {
#pragma unroll
        for (int fc = 0; fc < 4; ++fc) {
          int col = col_w + fc * 16 + lo;
          float v = acc[fr][fc][r];
          if (MODE != 0) v += bias[col];
          if (MODE == 2)
            ((float*)Cout)[(size_t)row * Ctot + col] = v;
          else
            ((unsigned short*)Cout)[(size_t)row * Ctot + col] = f2bf(v);
        }
      }
    }
  }
}

// ---------------- per-node attention scalars (from bf16 h) ----------------

template <int C>
__global__ void scalars_kernel(const unsigned short* __restrict__ h,
                               const float* __restrict__ a_src,
                               const float* __restrict__ a_dst, float* __restrict__ as_,
                               float* __restrict__ ad_, int N) {
  int wid = (blockIdx.x * blockDim.x + threadIdx.x) >> 6;
  int lane = threadIdx.x & 63;
  if (wid >= N) return;
  const int FPL = C / 64;
  const unsigned short* hr = h + (size_t)wid * C + FPL * lane;
  float s1 = 0.f, s2 = 0.f;
#pragma unroll
  for (int j = 0; j < FPL; ++j) {
    float v = bf2f(hr[j]);
    s1 += v * a_src[FPL * lane + j];
    s2 += v * a_dst[FPL * lane + j];
  }
#pragma unroll
  for (int off = 32; off; off >>= 1) {
    s1 += __shfl_xor(s1, off);
    s2 += __shfl_xor(s2, off);
  }
  if (lane == 0) {
    as_[wid] = s1;
    ad_[wid] = s2;
  }
}

// ---------------- per-dst online-softmax aggregation ----------------
// One wave per dst node. Gathers bf16 h rows; io buffer holds (res+bias) on
// entry and receives the final output (same-thread RMW). BF16IO: layer-1
// (C=128, bf16 io, relu). else layer-2 (C=256, fp32 io).

template <int C, bool BF16IO>
__global__ __launch_bounds__(256) void aggregate_kernel(
    const unsigned short* __restrict__ h, void* __restrict__ io,
    const float* __restrict__ as_, const float* __restrict__ ad_,
    const int* __restrict__ rowptr, const int* __restrict__ csr_src, int N) {
  const int FPL = C / 64;  // feats per lane
  int wid = blockIdx.x * 4 + (threadIdx.x >> 6);
  int lane = threadIdx.x & 63;
  if (wid >= N) return;
  int base = rowptr[wid];
  int deg = rowptr[wid + 1] - base;
  float adn = ad_[wid];
  float m = -1e30f, ssum = 0.f;
  float acc[FPL];
#pragma unroll
  for (int c = 0; c < FPL; ++c) acc[c] = 0.f;
  for (int b0 = 0; b0 < deg; b0 += 64) {
    int idx = b0 + lane;
    int s = 0;
    float logit = -1e30f;
    if (idx < deg) {
      s = csr_src[base + idx];
      float tt = as_[s] + adn;
      logit = tt > 0.f ? tt : 0.2f * tt;  // LeakyReLU 0.2
    }
    float cm = logit;
#pragma unroll
    for (int off = 32; off; off >>= 1) cm = fmaxf(cm, __shfl_xor(cm, off));
    float mnew = fmaxf(m, cm);
    float scale = __expf(m - mnew);
    ssum *= scale;
#pragma unroll
    for (int c = 0; c < FPL; ++c) acc[c] *= scale;
    float p = (idx < deg) ? __expf(logit - mnew) : 0.f;
    float ps = p;
#pragma unroll
    for (int off = 32; off; off >>= 1) ps += __shfl_xor(ps, off);
    ssum += ps;
    int cnt = min(64, deg - b0);
    for (int j = 0; j < cnt; ++j) {
      float pj = __shfl(p, j);
      int sj = __shfl(s, j);
      const unsigned short* hs = h + (size_t)sj * C + FPL * lane;
      if (FPL == 2) {
        ushort2 hv = *(const ushort2*)hs;
        acc[0] = fmaf(pj, bf2f(hv.x), acc[0]);
        acc[1] = fmaf(pj, bf2f(hv.y), acc[1]);
      } else {
        ushort4 hv = *(const ushort4*)hs;
        acc[0] = fmaf(pj, bf2f(hv.x), acc[0]);
        acc[1] = fmaf(pj, bf2f(hv.y), acc[1]);
        acc[2] = fmaf(pj, bf2f(hv.z), acc[2]);
        acc[3] = fmaf(pj, bf2f(hv.w), acc[3]);
      }
    }
    m = mnew;
  }
  float inv = 1.f / ssum;
  size_t o = (size_t)wid * C + FPL * lane;
  if (BF16IO) {
    unsigned short* p = (unsigned short*)io + o;
    ushort2 rv = *(const ushort2*)p;
    float v0 = acc[0] * inv + bf2f(rv.x);
    float v1 = acc[1] * inv + bf2f(rv.y);
    v0 = fmaxf(v0, 0.f);  // relu (layer 1)
    v1 = fmaxf(v1, 0.f);
    ushort2 ov; ov.x = f2bf(v0); ov.y = f2bf(v1);
    *(ushort2*)p = ov;
  } else {
    float* p = (float*)io + o;
    float4 rv = *(const float4*)p;
    float4 ov;
    ov.x = acc[0] * inv + rv.x;
    ov.y = acc[1] * inv + rv.y;
    ov.z = acc[2] * inv + rv.z;
    ov.w = acc[3] * inv + rv.w;
    *(float4*)p = ov;
  }
}

// ---------------- launch ----------------

extern "C" void kernel_launch(void* const* d_in, const int* in_sizes, int n_in,
                              void* d_out, int out_size, void* d_ws, size_t ws_size,
                              hipStream_t stream) {
  const float* x = (const float*)d_in[0];
  const void* edges = d_in[1];
  const float* W1 = (const float*)d_in[2];
  const float* a_src1 = (const float*)d_in[3];
  const float* a_dst1 = (const float*)d_in[4];
  const float* b1 = (const float*)d_in[5];
  const float* Wres1 = (const float*)d_in[6];
  const float* W2 = (const float*)d_in[7];
  const float* a_src2 = (const float*)d_in[8];
  const float* a_dst2 = (const float*)d_in[9];
  const float* b2 = (const float*)d_in[10];
  const float* Wres2 = (const float*)d_in[11];
  float* out = (float*)d_out;

  int N = in_sizes[0] / 128;
  int E = in_sizes[1] / 2;
  int TOT = E + N;
  int Mpad = (N + 127) & ~127;

  char* w = (char*)d_ws;
  size_t off = 0;
  auto alloc = [&](size_t bytes) {
    char* p = w + off;
    off += (bytes + 255) & ~(size_t)255;
    return p;
  };
  int* flag = (int*)alloc(4);
  int* counts = (int*)alloc((size_t)N * 4);
  int* cursor = (int*)alloc((size_t)N * 4);
  int* rowptr = (int*)alloc((size_t)(N + 1) * 4);
  float* as_ = (float*)alloc((size_t)N * 4);
  float* ad_ = (float*)alloc((size_t)N * 4);
  int* src32 = (int*)alloc((size_t)TOT * 4);
  int* dst32 = (int*)alloc((size_t)TOT * 4);
  int* csr = (int*)alloc((size_t)TOT * 4);
  unsigned short* x16 = (unsigned short*)alloc((size_t)Mpad * 128 * 2);
  unsigned short* w1t = (unsigned short*)alloc(128 * 128 * 2);
  unsigned short* wres1t = (unsigned short*)alloc(128 * 128 * 2);
  unsigned short* w2t = (unsigned short*)alloc(256 * 128 * 2);
  unsigned short* wres2t = (unsigned short*)alloc(256 * 128 * 2);
  unsigned short* h16 = (unsigned short*)alloc((size_t)N * 256 * 2);
  unsigned short* out1 = (unsigned short*)alloc((size_t)Mpad * 128 * 2);

  hipMemsetAsync(counts, 0, (size_t)N * 4, stream);
  // zero out1 pad rows (GEMM-2 A-loads read them)
  hipMemsetAsync(out1 + (size_t)N * 128, 0, (size_t)(Mpad - N) * 128 * 2, stream);

  detect_kernel<<<1, 1, 0, stream>>>(edges, N, flag);
  int gb = (TOT + 255) / 256;
  convert_kernel<<<gb, 256, 0, stream>>>(edges, E, N, flag, src32, dst32, counts);
  prefix_kernel<<<1, 1024, 0, stream>>>(counts, rowptr, cursor, N);
  scatter_kernel<<<gb, 256, 0, stream>>>(src32, dst32, cursor, csr, TOT);

  cvt_x_kernel<<<(Mpad * 32 + 255) / 256, 256, 0, stream>>>(x, x16, N, Mpad);
  cvt_wt_kernel<<<(128 * 128 + 255) / 256, 256, 0, stream>>>(W1, w1t, 128);
  cvt_wt_kernel<<<(128 * 128 + 255) / 256, 256, 0, stream>>>(Wres1, wres1t, 128);
  cvt_wt_kernel<<<(256 * 128 + 255) / 256, 256, 0, stream>>>(W2, w2t, 256);
  cvt_wt_kernel<<<(256 * 128 + 255) / 256, 256, 0, stream>>>(Wres2, wres2t, 256);

  int mt = Mpad / 128;
  int sb = (N + 3) / 4;

  // ---- layer 1 (C=128) ----
  gemm_mfma<0><<<dim3(mt, 1), 256, 0, stream>>>(x16, w1t, h16, nullptr, N, 128);
  gemm_mfma<1><<<dim3(mt, 1), 256, 0, stream>>>(x16, wres1t, out1, b1, N, 128);  // res1+b1 (bf16)
  scalars_kernel<128><<<sb, 256, 0, stream>>>(h16, a_src1, a_dst1, as_, ad_, N);
  aggregate_kernel<128, true><<<sb, 256, 0, stream>>>(h16, out1, as_, ad_, rowptr, csr, N);

  // ---- layer 2 (C=256) ----
  gemm_mfma<0><<<dim3(mt, 2), 256, 0, stream>>>(out1, w2t, h16, nullptr, N, 256);
  gemm_mfma<2><<<dim3(mt, 2), 256, 0, stream>>>(out1, wres2t, out, b2, N, 256);  // res2+b2 (fp32)
  scalars_kernel<256><<<sb, 256, 0, stream>>>(h16, a_src2, a_dst2, as_, ad_, N);
  aggregate_kernel<256, false><<<sb, 256, 0, stream>>>(h16, out, as_, ad_, rowptr, csr, N);
}

// Round 6
// 429.803 us; speedup vs baseline: 1.5920x; 1.2436x over previous
//
#include <hip/hip_runtime.h>
#include <math.h>

typedef __attribute__((ext_vector_type(8))) short bf16x8;
typedef __attribute__((ext_vector_type(4))) float f32x4;

__device__ inline unsigned short f2bf(float f) {
  union { float f; unsigned u; } x; x.f = f;
  unsigned r = x.u + 0x7FFF + ((x.u >> 16) & 1);
  return (unsigned short)(r >> 16);
}
__device__ inline float bf2f(unsigned short b) {
  union { unsigned u; float f; } x; x.u = ((unsigned)b) << 16;
  return x.f;
}

// ---------------- CSR build ----------------
// int64-vs-int32 detection inlined (uniform across all threads; int64 loads
// only execute when layout IS int64, so no OOB reads on int32 data).

__global__ void convert_kernel(const void* edges, int E, int N,
                               int* __restrict__ src32, int* __restrict__ dst32,
                               int* __restrict__ counts) {
  int i = blockIdx.x * blockDim.x + threadIdx.x;
  int tot = E + N;
  if (i >= tot) return;
  int s, d;
  if (i < E) {
    const long long* q = (const long long*)edges;
    bool i64 = true;
#pragma unroll
    for (int k = 0; k < 8; ++k) {
      long long v = q[k];
      if (v < 0 || v >= (long long)N) i64 = false;
    }
    if (i64) {
      s = (int)q[i];
      d = (int)q[E + i];
    } else {
      s = ((const int*)edges)[i];
      d = ((const int*)edges)[E + i];
    }
  } else {  // self loops
    s = d = i - E;
  }
  src32[i] = s;
  dst32[i] = d;
  atomicAdd(&counts[d], 1);
}

// ---- 3-phase parallel exclusive scan over counts[N] (1024 elems/block) ----

__global__ __launch_bounds__(256) void scan_partial(const int* __restrict__ counts,
                                                    int* __restrict__ bsum, int n) {
  int t = threadIdx.x;
  int base = blockIdx.x * 1024 + t * 4;
  int s = 0;
#pragma unroll
  for (int k = 0; k < 4; ++k) {
    int i = base + k;
    if (i < n) s += counts[i];
  }
#pragma unroll
  for (int off = 32; off; off >>= 1) s += __shfl_xor(s, off);
  __shared__ int red[4];
  if ((t & 63) == 0) red[t >> 6] = s;
  __syncthreads();
  if (t == 0) bsum[blockIdx.x] = red[0] + red[1] + red[2] + red[3];
}

// nblk <= 256 (N <= 262144). Also writes rowptr[n] = total.
__global__ __launch_bounds__(256) void scan_bsum(const int* __restrict__ bsum,
                                                 int* __restrict__ ebsum,
                                                 int* __restrict__ rowptr, int nblk, int n) {
  __shared__ int sh[256];
  int t = threadIdx.x;
  int v = (t < nblk) ? bsum[t] : 0;
  sh[t] = v;
  __syncthreads();
  for (int off = 1; off < 256; off <<= 1) {
    int u = (t >= off) ? sh[t - off] : 0;
    __syncthreads();
    sh[t] += u;
    __syncthreads();
  }
  if (t < nblk) ebsum[t] = sh[t] - v;
  if (t == nblk - 1) rowptr[n] = sh[t];
}

__global__ __launch_bounds__(256) void scan_final(const int* __restrict__ counts,
                                                  const int* __restrict__ ebsum,
                                                  int* __restrict__ rowptr,
                                                  int* __restrict__ cursor, int n) {
  int t = threadIdx.x;
  int lane = t & 63;
  int wv = t >> 6;
  int base = blockIdx.x * 1024 + t * 4;
  int c[4];
  int ts = 0;
#pragma unroll
  for (int k = 0; k < 4; ++k) {
    int i = base + k;
    c[k] = (i < n) ? counts[i] : 0;
    ts += c[k];
  }
  int ws = ts;  // wave inclusive scan
  for (int off = 1; off < 64; off <<= 1) {
    int u = __shfl_up(ws, off);
    if (lane >= off) ws += u;
  }
  __shared__ int wtot[4];
  if (lane == 63) wtot[wv] = ws;
  __syncthreads();
  int woff = 0;
  for (int k = 0; k < 4; ++k)
    if (k < wv) woff += wtot[k];
  int run = ebsum[blockIdx.x] + woff + (ws - ts);
#pragma unroll
  for (int k = 0; k < 4; ++k) {
    int i = base + k;
    if (i < n) {
      rowptr[i] = run;
      cursor[i] = run;
    }
    run += c[k];
  }
}

__global__ void scatter_kernel(const int* __restrict__ src32, const int* __restrict__ dst32,
                               int* __restrict__ cursor, int* __restrict__ csr_src, int tot) {
  int i = blockIdx.x * blockDim.x + threadIdx.x;
  if (i >= tot) return;
  int d = dst32[i];
  int slot = atomicAdd(&cursor[d], 1);
  csr_src[slot] = src32[i];
}

// ---------------- dtype conversion ----------------

__global__ void cvt_x_kernel(const float* __restrict__ x, unsigned short* __restrict__ x16,
                             int N, int Mpad) {
  int tid = blockIdx.x * blockDim.x + threadIdx.x;
  if (tid >= Mpad * 32) return;
  int row = tid >> 5;
  int q = (tid & 31) << 2;
  unsigned short o0 = 0, o1 = 0, o2 = 0, o3 = 0;
  if (row < N) {
    float4 v = *(const float4*)(x + (size_t)row * 128 + q);
    o0 = f2bf(v.x); o1 = f2bf(v.y); o2 = f2bf(v.z); o3 = f2bf(v.w);
  }
  unsigned short* p = x16 + (size_t)row * 128 + q;
  p[0] = o0; p[1] = o1; p[2] = o2; p[3] = o3;
}

// All four weights fp32 [128][C] -> bf16 [C][128] in one dispatch.
// Element space: [0,16384) W1, [16384,32768) Wres1, [32768,65536) W2, [65536,98304) Wres2.
__global__ void cvt_wt_all(const float* __restrict__ W1, const float* __restrict__ Wres1,
                           const float* __restrict__ W2, const float* __restrict__ Wres2,
                           unsigned short* __restrict__ w1t, unsigned short* __restrict__ wres1t,
                           unsigned short* __restrict__ w2t, unsigned short* __restrict__ wres2t) {
  int tid = blockIdx.x * blockDim.x + threadIdx.x;
  const float* W;
  unsigned short* Wt;
  int C, loc;
  if (tid < 16384) { W = W1; Wt = w1t; C = 128; loc = tid; }
  else if (tid < 32768) { W = Wres1; Wt = wres1t; C = 128; loc = tid - 16384; }
  else if (tid < 65536) { W = W2; Wt = w2t; C = 256; loc = tid - 32768; }
  else if (tid < 98304) { W = Wres2; Wt = wres2t; C = 256; loc = tid - 65536; }
  else return;
  int c = loc >> 7;
  int k = loc & 127;
  Wt[(size_t)c * 128 + k] = f2bf(W[(size_t)k * C + c]);
}

// ---------------- bf16 MFMA GEMM: [Mpad][128] @ Wt[C][128]^T ----------------
// No LDS: weights (<=64KB bf16) are L1/L2 resident; fragments loaded direct.
// Wave computes 64x64. MODE 0: bf16 store; 1: bf16 store+bias; 2: f32 store+bias.

template <int MODE>
__global__ __launch_bounds__(256) void gemm_mfma(const unsigned short* __restrict__ A,
                                                 const unsigned short* __restrict__ Bt,
                                                 void* __restrict__ Cout,
                                                 const float* __restrict__ bias,
                                                 int Nrows, int Ctot) {
  int l = threadIdx.x & 63;
  int w = threadIdx.x >> 6;
  int row_w = blockIdx.x * 128 + (w & 1) * 64;
  int col_w = blockIdx.y * 128 + (w >> 1) * 64;
  int lo = l & 15, hi = l >> 4;
  f32x4 acc[4][4];
#pragma unroll
  for (int i = 0; i < 4; ++i)
#pragma unroll
    for (int j = 0; j < 4; ++j) acc[i][j] = (f32x4){0.f, 0.f, 0.f, 0.f};

  const unsigned short* Ap = A + (size_t)(row_w + lo) * 128 + hi * 8;
  const unsigned short* Bp = Bt + (size_t)(col_w + lo) * 128 + hi * 8;
#pragma unroll
  for (int kk = 0; kk < 4; ++kk) {
    bf16x8 a[4], b[4];
#pragma unroll
    for (int f = 0; f < 4; ++f) {
      a[f] = *(const bf16x8*)(Ap + (size_t)f * 16 * 128 + kk * 32);
      b[f] = *(const bf16x8*)(Bp + (size_t)f * 16 * 128 + kk * 32);
    }
#pragma unroll
    for (int fr = 0; fr < 4; ++fr)
#pragma unroll
      for (int fc = 0; fc < 4; ++fc)
        acc[fr][fc] = __builtin_amdgcn_mfma_f32_16x16x32_bf16(a[fr], b[fc], acc[fr][fc], 0, 0, 0);
  }
  // D layout: col = lane&15, row = (lane>>4)*4 + reg   [m89-verified]
#pragma unroll
  for (int fr = 0; fr < 4; ++fr) {
#pragma unroll
    for (int r = 0; r < 4; ++r) {
      int row = row_w + fr * 16 + hi * 4 + r;
      if (row < Nrows) {
#pragma unroll
        for (int fc = 0; fc < 4; ++fc) {
          int col = col_w + fc * 16 + lo;
          float v = acc[fr][fc][r];
          if (MODE != 0) v += bias[col];
          if (MODE == 2)
            ((float*)Cout)[(size_t)row * Ctot + col] = v;
          else
            ((unsigned short*)Cout)[(size_t)row * Ctot + col] = f2bf(v);
        }
      }
    }
  }
}

// ---------------- per-node attention scalars (from bf16 h) ----------------

template <int C>
__global__ void scalars_kernel(const unsigned short* __restrict__ h,
                               const float* __restrict__ a_src,
                               const float* __restrict__ a_dst, float* __restrict__ as_,
                               float* __restrict__ ad_, int N) {
  int wid = (blockIdx.x * blockDim.x + threadIdx.x) >> 6;
  int lane = threadIdx.x & 63;
  if (wid >= N) return;
  const int FPL = C / 64;
  const unsigned short* hr = h + (size_t)wid * C + FPL * lane;
  float s1 = 0.f, s2 = 0.f;
#pragma unroll
  for (int j = 0; j < FPL; ++j) {
    float v = bf2f(hr[j]);
    s1 += v * a_src[FPL * lane + j];
    s2 += v * a_dst[FPL * lane + j];
  }
#pragma unroll
  for (int off = 32; off; off >>= 1) {
    s1 += __shfl_xor(s1, off);
    s2 += __shfl_xor(s2, off);
  }
  if (lane == 0) {
    as_[wid] = s1;
    ad_[wid] = s2;
  }
}

// ---------------- per-dst online-softmax aggregation ----------------

template <int C, bool BF16IO>
__global__ __launch_bounds__(256) void aggregate_kernel(
    const unsigned short* __restrict__ h, void* __restrict__ io,
    const float* __restrict__ as_, const float* __restrict__ ad_,
    const int* __restrict__ rowptr, const int* __restrict__ csr_src, int N) {
  const int FPL = C / 64;
  int wid = blockIdx.x * 4 + (threadIdx.x >> 6);
  int lane = threadIdx.x & 63;
  if (wid >= N) return;
  int base = rowptr[wid];
  int deg = rowptr[wid + 1] - base;
  float adn = ad_[wid];
  float m = -1e30f, ssum = 0.f;
  float acc[FPL];
#pragma unroll
  for (int c = 0; c < FPL; ++c) acc[c] = 0.f;
  for (int b0 = 0; b0 < deg; b0 += 64) {
    int idx = b0 + lane;
    int s = 0;
    float logit = -1e30f;
    if (idx < deg) {
      s = csr_src[base + idx];
      float tt = as_[s] + adn;
      logit = tt > 0.f ? tt : 0.2f * tt;  // LeakyReLU 0.2
    }
    float cm = logit;
#pragma unroll
    for (int off = 32; off; off >>= 1) cm = fmaxf(cm, __shfl_xor(cm, off));
    float mnew = fmaxf(m, cm);
    float scale = __expf(m - mnew);
    ssum *= scale;
#pragma unroll
    for (int c = 0; c < FPL; ++c) acc[c] *= scale;
    float p = (idx < deg) ? __expf(logit - mnew) : 0.f;
    float ps = p;
#pragma unroll
    for (int off = 32; off; off >>= 1) ps += __shfl_xor(ps, off);
    ssum += ps;
    int cnt = min(64, deg - b0);
    for (int j = 0; j < cnt; ++j) {
      float pj = __shfl(p, j);
      int sj = __shfl(s, j);
      const unsigned short* hs = h + (size_t)sj * C + FPL * lane;
      if (FPL == 2) {
        ushort2 hv = *(const ushort2*)hs;
        acc[0] = fmaf(pj, bf2f(hv.x), acc[0]);
        acc[1] = fmaf(pj, bf2f(hv.y), acc[1]);
      } else {
        ushort4 hv = *(const ushort4*)hs;
        acc[0] = fmaf(pj, bf2f(hv.x), acc[0]);
        acc[1] = fmaf(pj, bf2f(hv.y), acc[1]);
        acc[2] = fmaf(pj, bf2f(hv.z), acc[2]);
        acc[3] = fmaf(pj, bf2f(hv.w), acc[3]);
      }
    }
    m = mnew;
  }
  float inv = 1.f / ssum;
  size_t o = (size_t)wid * C + FPL * lane;
  if (BF16IO) {
    unsigned short* p = (unsigned short*)io + o;
    ushort2 rv = *(const ushort2*)p;
    float v0 = fmaxf(acc[0] * inv + bf2f(rv.x), 0.f);  // relu (layer 1)
    float v1 = fmaxf(acc[1] * inv + bf2f(rv.y), 0.f);
    ushort2 ov; ov.x = f2bf(v0); ov.y = f2bf(v1);
    *(ushort2*)p = ov;
  } else {
    float* p = (float*)io + o;
    float4 rv = *(const float4*)p;
    float4 ov;
    ov.x = acc[0] * inv + rv.x;
    ov.y = acc[1] * inv + rv.y;
    ov.z = acc[2] * inv + rv.z;
    ov.w = acc[3] * inv + rv.w;
    *(float4*)p = ov;
  }
}

// ---------------- launch ----------------

extern "C" void kernel_launch(void* const* d_in, const int* in_sizes, int n_in,
                              void* d_out, int out_size, void* d_ws, size_t ws_size,
                              hipStream_t stream) {
  const float* x = (const float*)d_in[0];
  const void* edges = d_in[1];
  const float* W1 = (const float*)d_in[2];
  const float* a_src1 = (const float*)d_in[3];
  const float* a_dst1 = (const float*)d_in[4];
  const float* b1 = (const float*)d_in[5];
  const float* Wres1 = (const float*)d_in[6];
  const float* W2 = (const float*)d_in[7];
  const float* a_src2 = (const float*)d_in[8];
  const float* a_dst2 = (const float*)d_in[9];
  const float* b2 = (const float*)d_in[10];
  const float* Wres2 = (const float*)d_in[11];
  float* out = (float*)d_out;

  int N = in_sizes[0] / 128;
  int E = in_sizes[1] / 2;
  int TOT = E + N;
  int Mpad = (N + 127) & ~127;
  int nblk = (N + 1023) >> 10;

  char* w = (char*)d_ws;
  size_t off = 0;
  auto alloc = [&](size_t bytes) {
    char* p = w + off;
    off += (bytes + 255) & ~(size_t)255;
    return p;
  };
  int* counts = (int*)alloc((size_t)N * 4);
  int* cursor = (int*)alloc((size_t)N * 4);
  int* rowptr = (int*)alloc((size_t)(N + 1) * 4);
  int* bsum = (int*)alloc(1024);
  int* ebsum = (int*)alloc(1024);
  float* as_ = (float*)alloc((size_t)N * 4);
  float* ad_ = (float*)alloc((size_t)N * 4);
  int* src32 = (int*)alloc((size_t)TOT * 4);
  int* dst32 = (int*)alloc((size_t)TOT * 4);
  int* csr = (int*)alloc((size_t)TOT * 4);
  unsigned short* x16 = (unsigned short*)alloc((size_t)Mpad * 128 * 2);
  unsigned short* w1t = (unsigned short*)alloc(128 * 128 * 2);
  unsigned short* wres1t = (unsigned short*)alloc(128 * 128 * 2);
  unsigned short* w2t = (unsigned short*)alloc(256 * 128 * 2);
  unsigned short* wres2t = (unsigned short*)alloc(256 * 128 * 2);
  unsigned short* h16 = (unsigned short*)alloc((size_t)N * 256 * 2);
  unsigned short* out1 = (unsigned short*)alloc((size_t)Mpad * 128 * 2);

  hipMemsetAsync(counts, 0, (size_t)N * 4, stream);
  hipMemsetAsync(out1 + (size_t)N * 128, 0, (size_t)(Mpad - N) * 128 * 2, stream);

  int gb = (TOT + 255) / 256;
  convert_kernel<<<gb, 256, 0, stream>>>(edges, E, N, src32, dst32, counts);
  scan_partial<<<nblk, 256, 0, stream>>>(counts, bsum, N);
  scan_bsum<<<1, 256, 0, stream>>>(bsum, ebsum, rowptr, nblk, N);
  scan_final<<<nblk, 256, 0, stream>>>(counts, ebsum, rowptr, cursor, N);
  scatter_kernel<<<gb, 256, 0, stream>>>(src32, dst32, cursor, csr, TOT);

  cvt_x_kernel<<<(Mpad * 32 + 255) / 256, 256, 0, stream>>>(x, x16, N, Mpad);
  cvt_wt_all<<<(98304 + 255) / 256, 256, 0, stream>>>(W1, Wres1, W2, Wres2, w1t, wres1t, w2t, wres2t);

  int mt = Mpad / 128;
  int sb = (N + 3) / 4;

  // ---- layer 1 (C=128) ----
  gemm_mfma<0><<<dim3(mt, 1), 256, 0, stream>>>(x16, w1t, h16, nullptr, N, 128);
  gemm_mfma<1><<<dim3(mt, 1), 256, 0, stream>>>(x16, wres1t, out1, b1, N, 128);
  scalars_kernel<128><<<sb, 256, 0, stream>>>(h16, a_src1, a_dst1, as_, ad_, N);
  aggregate_kernel<128, true><<<sb, 256, 0, stream>>>(h16, out1, as_, ad_, rowptr, csr, N);

  // ---- layer 2 (C=256) ----
  gemm_mfma<0><<<dim3(mt, 2), 256, 0, stream>>>(out1, w2t, h16, nullptr, N, 256);
  gemm_mfma<2><<<dim3(mt, 2), 256, 0, stream>>>(out1, wres2t, out, b2, N, 256);
  scalars_kernel<256><<<sb, 256, 0, stream>>>(h16, a_src2, a_dst2, as_, ad_, N);
  aggregate_kernel<256, false><<<sb, 256, 0, stream>>>(h16, out, as_, ad_, rowptr, csr, N);
}

// Round 7
// 387.876 us; speedup vs baseline: 1.7641x; 1.1081x over previous
//
#include <hip/hip_runtime.h>
#include <math.h>

typedef __attribute__((ext_vector_type(8))) short bf16x8;
typedef __attribute__((ext_vector_type(4))) float f32x4;

__device__ inline unsigned short f2bf(float f) {
  union { float f; unsigned u; } x; x.f = f;
  unsigned r = x.u + 0x7FFF + ((x.u >> 16) & 1);
  return (unsigned short)(r >> 16);
}
__device__ inline float bf2f(unsigned short b) {
  union { unsigned u; float f; } x; x.u = ((unsigned)b) << 16;
  return x.f;
}

// ---------------- CSR build ----------------

__global__ void convert_kernel(const void* edges, int E, int N,
                               int* __restrict__ src32, int* __restrict__ dst32,
                               int* __restrict__ counts) {
  int i = blockIdx.x * blockDim.x + threadIdx.x;
  int tot = E + N;
  if (i >= tot) return;
  int s, d;
  if (i < E) {
    const long long* q = (const long long*)edges;
    bool i64 = true;
#pragma unroll
    for (int k = 0; k < 8; ++k) {
      long long v = q[k];
      if (v < 0 || v >= (long long)N) i64 = false;
    }
    if (i64) {
      s = (int)q[i];
      d = (int)q[E + i];
    } else {
      s = ((const int*)edges)[i];
      d = ((const int*)edges)[E + i];
    }
  } else {  // self loops
    s = d = i - E;
  }
  src32[i] = s;
  dst32[i] = d;
  atomicAdd(&counts[d], 1);
}

// ---- 3-phase parallel exclusive scan over counts[N] (1024 elems/block) ----

__global__ __launch_bounds__(256) void scan_partial(const int* __restrict__ counts,
                                                    int* __restrict__ bsum, int n) {
  int t = threadIdx.x;
  int base = blockIdx.x * 1024 + t * 4;
  int s = 0;
#pragma unroll
  for (int k = 0; k < 4; ++k) {
    int i = base + k;
    if (i < n) s += counts[i];
  }
#pragma unroll
  for (int off = 32; off; off >>= 1) s += __shfl_xor(s, off);
  __shared__ int red[4];
  if ((t & 63) == 0) red[t >> 6] = s;
  __syncthreads();
  if (t == 0) bsum[blockIdx.x] = red[0] + red[1] + red[2] + red[3];
}

__global__ __launch_bounds__(256) void scan_bsum(const int* __restrict__ bsum,
                                                 int* __restrict__ ebsum,
                                                 int* __restrict__ rowptr, int nblk, int n) {
  __shared__ int sh[256];
  int t = threadIdx.x;
  int v = (t < nblk) ? bsum[t] : 0;
  sh[t] = v;
  __syncthreads();
  for (int off = 1; off < 256; off <<= 1) {
    int u = (t >= off) ? sh[t - off] : 0;
    __syncthreads();
    sh[t] += u;
    __syncthreads();
  }
  if (t < nblk) ebsum[t] = sh[t] - v;
  if (t == nblk - 1) rowptr[n] = sh[t];
}

__global__ __launch_bounds__(256) void scan_final(const int* __restrict__ counts,
                                                  const int* __restrict__ ebsum,
                                                  int* __restrict__ rowptr,
                                                  int* __restrict__ cursor, int n) {
  int t = threadIdx.x;
  int lane = t & 63;
  int wv = t >> 6;
  int base = blockIdx.x * 1024 + t * 4;
  int c[4];
  int ts = 0;
#pragma unroll
  for (int k = 0; k < 4; ++k) {
    int i = base + k;
    c[k] = (i < n) ? counts[i] : 0;
    ts += c[k];
  }
  int ws = ts;
  for (int off = 1; off < 64; off <<= 1) {
    int u = __shfl_up(ws, off);
    if (lane >= off) ws += u;
  }
  __shared__ int wtot[4];
  if (lane == 63) wtot[wv] = ws;
  __syncthreads();
  int woff = 0;
  for (int k = 0; k < 4; ++k)
    if (k < wv) woff += wtot[k];
  int run = ebsum[blockIdx.x] + woff + (ws - ts);
#pragma unroll
  for (int k = 0; k < 4; ++k) {
    int i = base + k;
    if (i < n) {
      rowptr[i] = run;
      cursor[i] = run;
    }
    run += c[k];
  }
}

__global__ void scatter_kernel(const int* __restrict__ src32, const int* __restrict__ dst32,
                               int* __restrict__ cursor, int* __restrict__ csr_src, int tot) {
  int i = blockIdx.x * blockDim.x + threadIdx.x;
  if (i >= tot) return;
  int d = dst32[i];
  int slot = atomicAdd(&cursor[d], 1);
  csr_src[slot] = src32[i];
}

// ---------------- fused dtype conversion (x + all 4 weights) ----------------
// tid < Mpad*32: x fp32 [N][128] -> bf16 [Mpad][128] (pad rows zero), 4 elem/thr.
// else: weights fp32 [128][C] -> bf16 [C][128].

__global__ void cvt_all(const float* __restrict__ x,
                        const float* __restrict__ W1, const float* __restrict__ Wres1,
                        const float* __restrict__ W2, const float* __restrict__ Wres2,
                        unsigned short* __restrict__ x16,
                        unsigned short* __restrict__ w1t, unsigned short* __restrict__ wres1t,
                        unsigned short* __restrict__ w2t, unsigned short* __restrict__ wres2t,
                        int N, int Mpad) {
  int tid = blockIdx.x * blockDim.x + threadIdx.x;
  int xcnt = Mpad * 32;
  if (tid < xcnt) {
    int row = tid >> 5;
    int q = (tid & 31) << 2;
    unsigned short o0 = 0, o1 = 0, o2 = 0, o3 = 0;
    if (row < N) {
      float4 v = *(const float4*)(x + (size_t)row * 128 + q);
      o0 = f2bf(v.x); o1 = f2bf(v.y); o2 = f2bf(v.z); o3 = f2bf(v.w);
    }
    unsigned short* p = x16 + (size_t)row * 128 + q;
    p[0] = o0; p[1] = o1; p[2] = o2; p[3] = o3;
    return;
  }
  int t2 = tid - xcnt;
  const float* W;
  unsigned short* Wt;
  int C, loc;
  if (t2 < 16384) { W = W1; Wt = w1t; C = 128; loc = t2; }
  else if (t2 < 32768) { W = Wres1; Wt = wres1t; C = 128; loc = t2 - 16384; }
  else if (t2 < 65536) { W = W2; Wt = w2t; C = 256; loc = t2 - 32768; }
  else if (t2 < 98304) { W = Wres2; Wt = wres2t; C = 256; loc = t2 - 65536; }
  else return;
  int c = loc >> 7;
  int k = loc & 127;
  Wt[(size_t)c * 128 + k] = f2bf(W[(size_t)k * C + c]);
}

// ---------------- bf16 MFMA GEMM: [Mpad][128] @ Wt[C][128]^T ----------------
// MODE 0: bf16 store; 1: bf16 store + bias.

template <int MODE>
__global__ __launch_bounds__(256) void gemm_mfma(const unsigned short* __restrict__ A,
                                                 const unsigned short* __restrict__ Bt,
                                                 unsigned short* __restrict__ Cout,
                                                 const float* __restrict__ bias,
                                                 int Nrows, int Ctot) {
  int l = threadIdx.x & 63;
  int w = threadIdx.x >> 6;
  int row_w = blockIdx.x * 128 + (w & 1) * 64;
  int col_w = blockIdx.y * 128 + (w >> 1) * 64;
  int lo = l & 15, hi = l >> 4;
  f32x4 acc[4][4];
#pragma unroll
  for (int i = 0; i < 4; ++i)
#pragma unroll
    for (int j = 0; j < 4; ++j) acc[i][j] = (f32x4){0.f, 0.f, 0.f, 0.f};

  const unsigned short* Ap = A + (size_t)(row_w + lo) * 128 + hi * 8;
  const unsigned short* Bp = Bt + (size_t)(col_w + lo) * 128 + hi * 8;
#pragma unroll
  for (int kk = 0; kk < 4; ++kk) {
    bf16x8 a[4], b[4];
#pragma unroll
    for (int f = 0; f < 4; ++f) {
      a[f] = *(const bf16x8*)(Ap + (size_t)f * 16 * 128 + kk * 32);
      b[f] = *(const bf16x8*)(Bp + (size_t)f * 16 * 128 + kk * 32);
    }
#pragma unroll
    for (int fr = 0; fr < 4; ++fr)
#pragma unroll
      for (int fc = 0; fc < 4; ++fc)
        acc[fr][fc] = __builtin_amdgcn_mfma_f32_16x16x32_bf16(a[fr], b[fc], acc[fr][fc], 0, 0, 0);
  }
  // D layout: col = lane&15, row = (lane>>4)*4 + reg   [m89-verified]
#pragma unroll
  for (int fr = 0; fr < 4; ++fr) {
#pragma unroll
    for (int r = 0; r < 4; ++r) {
      int row = row_w + fr * 16 + hi * 4 + r;
      if (row < Nrows) {
#pragma unroll
        for (int fc = 0; fc < 4; ++fc) {
          int col = col_w + fc * 16 + lo;
          float v = acc[fr][fc][r];
          if (MODE == 1) v += bias[col];
          Cout[(size_t)row * Ctot + col] = f2bf(v);
        }
      }
    }
  }
}

// ---------------- per-node attention scalars (from bf16 h) ----------------

template <int C>
__global__ void scalars_kernel(const unsigned short* __restrict__ h,
                               const float* __restrict__ a_src,
                               const float* __restrict__ a_dst, float* __restrict__ as_,
                               float* __restrict__ ad_, int N) {
  int wid = (blockIdx.x * blockDim.x + threadIdx.x) >> 6;
  int lane = threadIdx.x & 63;
  if (wid >= N) return;
  const int FPL = C / 64;
  const unsigned short* hr = h + (size_t)wid * C + FPL * lane;
  float s1 = 0.f, s2 = 0.f;
#pragma unroll
  for (int j = 0; j < FPL; ++j) {
    float v = bf2f(hr[j]);
    s1 += v * a_src[FPL * lane + j];
    s2 += v * a_dst[FPL * lane + j];
  }
#pragma unroll
  for (int off = 32; off; off >>= 1) {
    s1 += __shfl_xor(s1, off);
    s2 += __shfl_xor(s2, off);
  }
  if (lane == 0) {
    as_[wid] = s1;
    ad_[wid] = s2;
  }
}

// ---------------- per-dst online-softmax aggregation ----------------
// One wave per dst node; 4x-unrolled gather for memory-level parallelism.
// L1: res bf16 (in-place RMW on `res`), +relu, bf16 out.
// !L1: res bf16 (separate buf), fp32 out to `outf`.

template <int C, bool L1>
__global__ __launch_bounds__(256) void aggregate_kernel(
    const unsigned short* __restrict__ h, unsigned short* __restrict__ res,
    float* __restrict__ outf,
    const float* __restrict__ as_, const float* __restrict__ ad_,
    const int* __restrict__ rowptr, const int* __restrict__ csr_src, int N) {
  const int FPL = C / 64;
  int wid = blockIdx.x * 4 + (threadIdx.x >> 6);
  int lane = threadIdx.x & 63;
  if (wid >= N) return;
  int base = rowptr[wid];
  int deg = rowptr[wid + 1] - base;
  float adn = ad_[wid];
  float m = -1e30f, ssum = 0.f;
  float acc[FPL];
#pragma unroll
  for (int c = 0; c < FPL; ++c) acc[c] = 0.f;
  for (int b0 = 0; b0 < deg; b0 += 64) {
    int idx = b0 + lane;
    int s = 0;
    float logit = -1e30f;
    if (idx < deg) {
      s = csr_src[base + idx];
      float tt = as_[s] + adn;
      logit = tt > 0.f ? tt : 0.2f * tt;  // LeakyReLU 0.2
    }
    float cm = logit;
#pragma unroll
    for (int off = 32; off; off >>= 1) cm = fmaxf(cm, __shfl_xor(cm, off));
    float mnew = fmaxf(m, cm);
    float scale = __expf(m - mnew);
    ssum *= scale;
#pragma unroll
    for (int c = 0; c < FPL; ++c) acc[c] *= scale;
    float p = (idx < deg) ? __expf(logit - mnew) : 0.f;
    float ps = p;
#pragma unroll
    for (int off = 32; off; off >>= 1) ps += __shfl_xor(ps, off);
    ssum += ps;
    int cnt = min(64, deg - b0);
    int j = 0;
    for (; j + 4 <= cnt; j += 4) {
      float pj0 = __shfl(p, j), pj1 = __shfl(p, j + 1);
      float pj2 = __shfl(p, j + 2), pj3 = __shfl(p, j + 3);
      int sj0 = __shfl(s, j), sj1 = __shfl(s, j + 1);
      int sj2 = __shfl(s, j + 2), sj3 = __shfl(s, j + 3);
      const unsigned short* h0 = h + (size_t)sj0 * C + FPL * lane;
      const unsigned short* h1 = h + (size_t)sj1 * C + FPL * lane;
      const unsigned short* h2 = h + (size_t)sj2 * C + FPL * lane;
      const unsigned short* h3 = h + (size_t)sj3 * C + FPL * lane;
      if (FPL == 2) {
        ushort2 v0 = *(const ushort2*)h0, v1 = *(const ushort2*)h1;
        ushort2 v2 = *(const ushort2*)h2, v3 = *(const ushort2*)h3;
        acc[0] = fmaf(pj0, bf2f(v0.x), acc[0]); acc[1] = fmaf(pj0, bf2f(v0.y), acc[1]);
        acc[0] = fmaf(pj1, bf2f(v1.x), acc[0]); acc[1] = fmaf(pj1, bf2f(v1.y), acc[1]);
        acc[0] = fmaf(pj2, bf2f(v2.x), acc[0]); acc[1] = fmaf(pj2, bf2f(v2.y), acc[1]);
        acc[0] = fmaf(pj3, bf2f(v3.x), acc[0]); acc[1] = fmaf(pj3, bf2f(v3.y), acc[1]);
      } else {
        ushort4 v0 = *(const ushort4*)h0, v1 = *(const ushort4*)h1;
        ushort4 v2 = *(const ushort4*)h2, v3 = *(const ushort4*)h3;
        acc[0] = fmaf(pj0, bf2f(v0.x), acc[0]); acc[1] = fmaf(pj0, bf2f(v0.y), acc[1]);
        acc[2] = fmaf(pj0, bf2f(v0.z), acc[2]); acc[3] = fmaf(pj0, bf2f(v0.w), acc[3]);
        acc[0] = fmaf(pj1, bf2f(v1.x), acc[0]); acc[1] = fmaf(pj1, bf2f(v1.y), acc[1]);
        acc[2] = fmaf(pj1, bf2f(v1.z), acc[2]); acc[3] = fmaf(pj1, bf2f(v1.w), acc[3]);
        acc[0] = fmaf(pj2, bf2f(v2.x), acc[0]); acc[1] = fmaf(pj2, bf2f(v2.y), acc[1]);
        acc[2] = fmaf(pj2, bf2f(v2.z), acc[2]); acc[3] = fmaf(pj2, bf2f(v2.w), acc[3]);
        acc[0] = fmaf(pj3, bf2f(v3.x), acc[0]); acc[1] = fmaf(pj3, bf2f(v3.y), acc[1]);
        acc[2] = fmaf(pj3, bf2f(v3.z), acc[2]); acc[3] = fmaf(pj3, bf2f(v3.w), acc[3]);
      }
    }
    for (; j < cnt; ++j) {
      float pj = __shfl(p, j);
      int sj = __shfl(s, j);
      const unsigned short* hs = h + (size_t)sj * C + FPL * lane;
      if (FPL == 2) {
        ushort2 hv = *(const ushort2*)hs;
        acc[0] = fmaf(pj, bf2f(hv.x), acc[0]);
        acc[1] = fmaf(pj, bf2f(hv.y), acc[1]);
      } else {
        ushort4 hv = *(const ushort4*)hs;
        acc[0] = fmaf(pj, bf2f(hv.x), acc[0]);
        acc[1] = fmaf(pj, bf2f(hv.y), acc[1]);
        acc[2] = fmaf(pj, bf2f(hv.z), acc[2]);
        acc[3] = fmaf(pj, bf2f(hv.w), acc[3]);
      }
    }
    m = mnew;
  }
  float inv = 1.f / ssum;
  size_t o = (size_t)wid * C + FPL * lane;
  if (L1) {
    unsigned short* p = res + o;
    ushort2 rv = *(const ushort2*)p;
    float v0 = fmaxf(acc[0] * inv + bf2f(rv.x), 0.f);  // relu
    float v1 = fmaxf(acc[1] * inv + bf2f(rv.y), 0.f);
    ushort2 ov; ov.x = f2bf(v0); ov.y = f2bf(v1);
    *(ushort2*)p = ov;
  } else {
    ushort4 rv = *(const ushort4*)(res + o);
    float4 ov;
    ov.x = acc[0] * inv + bf2f(rv.x);
    ov.y = acc[1] * inv + bf2f(rv.y);
    ov.z = acc[2] * inv + bf2f(rv.z);
    ov.w = acc[3] * inv + bf2f(rv.w);
    *(float4*)(outf + o) = ov;
  }
}

// ---------------- launch ----------------

extern "C" void kernel_launch(void* const* d_in, const int* in_sizes, int n_in,
                              void* d_out, int out_size, void* d_ws, size_t ws_size,
                              hipStream_t stream) {
  const float* x = (const float*)d_in[0];
  const void* edges = d_in[1];
  const float* W1 = (const float*)d_in[2];
  const float* a_src1 = (const float*)d_in[3];
  const float* a_dst1 = (const float*)d_in[4];
  const float* b1 = (const float*)d_in[5];
  const float* Wres1 = (const float*)d_in[6];
  const float* W2 = (const float*)d_in[7];
  const float* a_src2 = (const float*)d_in[8];
  const float* a_dst2 = (const float*)d_in[9];
  const float* b2 = (const float*)d_in[10];
  const float* Wres2 = (const float*)d_in[11];
  float* out = (float*)d_out;

  int N = in_sizes[0] / 128;
  int E = in_sizes[1] / 2;
  int TOT = E + N;
  int Mpad = (N + 127) & ~127;
  int nblk = (N + 1023) >> 10;

  char* w = (char*)d_ws;
  size_t off = 0;
  auto alloc = [&](size_t bytes) {
    char* p = w + off;
    off += (bytes + 255) & ~(size_t)255;
    return p;
  };
  int* counts = (int*)alloc((size_t)N * 4);
  int* cursor = (int*)alloc((size_t)N * 4);
  int* rowptr = (int*)alloc((size_t)(N + 1) * 4);
  int* bsum = (int*)alloc(1024);
  int* ebsum = (int*)alloc(1024);
  float* as_ = (float*)alloc((size_t)N * 4);
  float* ad_ = (float*)alloc((size_t)N * 4);
  int* src32 = (int*)alloc((size_t)TOT * 4);
  int* dst32 = (int*)alloc((size_t)TOT * 4);
  int* csr = (int*)alloc((size_t)TOT * 4);
  unsigned short* x16 = (unsigned short*)alloc((size_t)Mpad * 128 * 2);
  unsigned short* w1t = (unsigned short*)alloc(128 * 128 * 2);
  unsigned short* wres1t = (unsigned short*)alloc(128 * 128 * 2);
  unsigned short* w2t = (unsigned short*)alloc(256 * 128 * 2);
  unsigned short* wres2t = (unsigned short*)alloc(256 * 128 * 2);
  unsigned short* h16 = (unsigned short*)alloc((size_t)N * 256 * 2);
  unsigned short* out1 = (unsigned short*)alloc((size_t)Mpad * 128 * 2);
  unsigned short* res2 = (unsigned short*)alloc((size_t)Mpad * 256 * 2);

  hipMemsetAsync(counts, 0, (size_t)N * 4, stream);
  hipMemsetAsync(out1 + (size_t)N * 128, 0, (size_t)(Mpad - N) * 128 * 2, stream);

  int gb = (TOT + 255) / 256;
  convert_kernel<<<gb, 256, 0, stream>>>(edges, E, N, src32, dst32, counts);
  scan_partial<<<nblk, 256, 0, stream>>>(counts, bsum, N);
  scan_bsum<<<1, 256, 0, stream>>>(bsum, ebsum, rowptr, nblk, N);
  scan_final<<<nblk, 256, 0, stream>>>(counts, ebsum, rowptr, cursor, N);
  scatter_kernel<<<gb, 256, 0, stream>>>(src32, dst32, cursor, csr, TOT);

  cvt_all<<<(Mpad * 32 + 98304 + 255) / 256, 256, 0, stream>>>(
      x, W1, Wres1, W2, Wres2, x16, w1t, wres1t, w2t, wres2t, N, Mpad);

  int mt = Mpad / 128;
  int sb = (N + 3) / 4;

  // ---- layer 1 (C=128) ----
  gemm_mfma<0><<<dim3(mt, 1), 256, 0, stream>>>(x16, w1t, h16, nullptr, N, 128);
  gemm_mfma<1><<<dim3(mt, 1), 256, 0, stream>>>(x16, wres1t, out1, b1, N, 128);
  scalars_kernel<128><<<sb, 256, 0, stream>>>(h16, a_src1, a_dst1, as_, ad_, N);
  aggregate_kernel<128, true><<<sb, 256, 0, stream>>>(h16, out1, nullptr, as_, ad_, rowptr, csr, N);

  // ---- layer 2 (C=256) ----
  gemm_mfma<0><<<dim3(mt, 2), 256, 0, stream>>>(out1, w2t, h16, nullptr, N, 256);
  gemm_mfma<1><<<dim3(mt, 2), 256, 0, stream>>>(out1, wres2t, res2, b2, N, 256);
  scalars_kernel<256><<<sb, 256, 0, stream>>>(h16, a_src2, a_dst2, as_, ad_, N);
  aggregate_kernel<256, false><<<sb, 256, 0, stream>>>(h16, res2, out, as_, ad_, rowptr, csr, N);
}